// Round 1
// baseline (566.674 us; speedup 1.0000x reference)
//
#include <hip/hip_runtime.h>
#include <math.h>

#define NQ_   32
#define M_    32
#define ND_   200
#define N_    160
#define H_    768
#define DIM_  128

// ---------------------------------------------------------------------------
// Q projection: one block per row (1024 blocks), 128 threads = 128 output cols.
// W (768x128) is L2-resident; X row broadcast via scalar loads.
// ---------------------------------------------------------------------------
__global__ __launch_bounds__(128) void proj_norm_row_kernel(
    const float* __restrict__ X, const float* __restrict__ W,
    float* __restrict__ Y)
{
    const int row = blockIdx.x;
    const int c   = threadIdx.x;            // 0..127
    const float* x = X + (size_t)row * H_;
    float acc = 0.0f;
#pragma unroll 8
    for (int h = 0; h < H_; ++h)
        acc = fmaf(x[h], W[(size_t)h * DIM_ + c], acc);

    // sum of squares across 128 threads (2 waves)
    float ss = __fmul_rn(acc, acc);
    ss = __fadd_rn(ss, __shfl_xor(ss, 1));
    ss = __fadd_rn(ss, __shfl_xor(ss, 2));
    ss = __fadd_rn(ss, __shfl_xor(ss, 4));
    ss = __fadd_rn(ss, __shfl_xor(ss, 8));
    ss = __fadd_rn(ss, __shfl_xor(ss, 16));
    ss = __fadd_rn(ss, __shfl_xor(ss, 32));
    __shared__ float sred[2];
    if ((c & 63) == 0) sred[c >> 6] = ss;
    __syncthreads();
    float tot = __fadd_rn(sred[0], sred[1]);
    float nrm = fmaxf(sqrtf(tot), 1e-12f);
    Y[(size_t)row * DIM_ + c] = acc / nrm;  // IEEE divide, matches np x/norm
}

// ---------------------------------------------------------------------------
// D projection: tiled GEMM + row L2-normalize.
// Block 256 threads; tile 128 rows x 128 cols; K chunks of 16.
// Thread (rg=tid/16, cg=tid%16) owns an 8x8 register tile.
// ---------------------------------------------------------------------------
__global__ __launch_bounds__(256) void proj_norm_tiled_kernel(
    const float* __restrict__ X, const float* __restrict__ W,
    float* __restrict__ Y)
{
    __shared__ float Xt[16][128];   // [k][row] (transposed)
    __shared__ float Ws[16][128];   // [k][col]
    const int tid = threadIdx.x;
    const int rb  = blockIdx.x * 128;
    const int cg  = tid & 15;
    const int rg  = tid >> 4;

    float acc[8][8];
#pragma unroll
    for (int i = 0; i < 8; ++i)
#pragma unroll
        for (int j = 0; j < 8; ++j) acc[i][j] = 0.0f;

    for (int kc = 0; kc < H_; kc += 16) {
#pragma unroll
        for (int it = 0; it < 2; ++it) {
            int f = tid + it * 256;           // 512 float4s of the X chunk
            int row = f >> 2;
            int c4  = f & 3;
            float4 v = *reinterpret_cast<const float4*>(
                &X[(size_t)(rb + row) * H_ + kc + c4 * 4]);
            Xt[c4*4+0][row] = v.x;
            Xt[c4*4+1][row] = v.y;
            Xt[c4*4+2][row] = v.z;
            Xt[c4*4+3][row] = v.w;
        }
#pragma unroll
        for (int it = 0; it < 2; ++it) {
            int f = tid + it * 256;           // 512 float4s of the W chunk
            int wr = f >> 5;
            int wc = f & 31;
            float4 v = *reinterpret_cast<const float4*>(
                &W[(size_t)(kc + wr) * DIM_ + wc * 4]);
            *reinterpret_cast<float4*>(&Ws[wr][wc * 4]) = v;
        }
        __syncthreads();
#pragma unroll
        for (int k = 0; k < 16; ++k) {
            float a[8], b[8];
            *reinterpret_cast<float4*>(&a[0]) = *reinterpret_cast<const float4*>(&Xt[k][rg*8]);
            *reinterpret_cast<float4*>(&a[4]) = *reinterpret_cast<const float4*>(&Xt[k][rg*8+4]);
            *reinterpret_cast<float4*>(&b[0]) = *reinterpret_cast<const float4*>(&Ws[k][cg*8]);
            *reinterpret_cast<float4*>(&b[4]) = *reinterpret_cast<const float4*>(&Ws[k][cg*8+4]);
#pragma unroll
            for (int i = 0; i < 8; ++i)
#pragma unroll
                for (int j = 0; j < 8; ++j)
                    acc[i][j] = fmaf(a[i], b[j], acc[i][j]);
        }
        __syncthreads();
    }

    // normalize each row (row spread across the 16 cg lanes; same-rg lanes are
    // 16 consecutive lanes of one wave). Butterfly matches numpy pairwise sum.
#pragma unroll
    for (int i = 0; i < 8; ++i) {
        float ss = 0.0f;
#pragma unroll
        for (int j = 0; j < 8; ++j) ss = __fadd_rn(ss, __fmul_rn(acc[i][j], acc[i][j]));
        ss = __fadd_rn(ss, __shfl_xor(ss, 1));
        ss = __fadd_rn(ss, __shfl_xor(ss, 2));
        ss = __fadd_rn(ss, __shfl_xor(ss, 4));
        ss = __fadd_rn(ss, __shfl_xor(ss, 8));
        float nrm = fmaxf(sqrtf(ss), 1e-12f);
        float o[8];
#pragma unroll
        for (int j = 0; j < 8; ++j) o[j] = acc[i][j] / nrm;
        size_t base = (size_t)(rb + rg*8 + i) * DIM_ + cg*8;
        *reinterpret_cast<float4*>(&Y[base])     = *reinterpret_cast<float4*>(&o[0]);
        *reinterpret_cast<float4*>(&Y[base + 4]) = *reinterpret_cast<float4*>(&o[4]);
    }
}

// ---------------------------------------------------------------------------
// Score kernel: block = 256 threads = 4 waves. Wave w handles d = 4*db + w.
// Each wave computes S[32][160] = Qp[q] · Dp[d]^T with per-lane 8x10 tile
// (mg=lane/16 -> rows mg*8..+7, ng=lane%16 -> cols ng*10..+9), then the
// log_softmax + gumbel argmax per row entirely in registers/shuffles.
// ---------------------------------------------------------------------------
__global__ __launch_bounds__(256) void score_kernel(
    const float* __restrict__ Qp, const float* __restrict__ Dp,
    const float* __restrict__ qmask, const float* __restrict__ dmask,
    const float* __restrict__ gum, float* __restrict__ out)
{
    __shared__ float Qt[16][32];        // [k][m]
    __shared__ float Dt[4][16][164];    // [wave][k][n], pad 160->164 (2-way writes)
    const int tid  = threadIdx.x;
    const int w    = tid >> 6;
    const int lane = tid & 63;
    const int mg   = lane >> 4;
    const int ng   = lane & 15;
    const int q    = blockIdx.x & 31;   // q fast: concurrent blocks share Dp set
    const int db   = blockIdx.x >> 5;   // 0..49
    const int d    = db * 4 + w;

    const float* Qb = Qp + (size_t)q * M_ * DIM_;
    const float* Db = Dp + (size_t)d * N_ * DIM_;

    float acc[8][10];
#pragma unroll
    for (int i = 0; i < 8; ++i)
#pragma unroll
        for (int j = 0; j < 10; ++j) acc[i][j] = 0.0f;

    for (int kc = 0; kc < DIM_; kc += 16) {
        if (tid < 128) {                        // 128 float4 = 32 m x 16 k
            int m = tid >> 2, c4 = tid & 3;
            float4 v = *reinterpret_cast<const float4*>(&Qb[(size_t)m * DIM_ + kc + c4*4]);
            Qt[c4*4+0][m] = v.x;
            Qt[c4*4+1][m] = v.y;
            Qt[c4*4+2][m] = v.z;
            Qt[c4*4+3][m] = v.w;
        }
#pragma unroll
        for (int it = 0; it < 10; ++it) {       // 640 float4 = 160 n x 16 k per wave
            int f = lane + it * 64;
            int n = f >> 2, c4 = f & 3;
            float4 v = *reinterpret_cast<const float4*>(&Db[(size_t)n * DIM_ + kc + c4*4]);
            Dt[w][c4*4+0][n] = v.x;
            Dt[w][c4*4+1][n] = v.y;
            Dt[w][c4*4+2][n] = v.z;
            Dt[w][c4*4+3][n] = v.w;
        }
        __syncthreads();
#pragma unroll
        for (int k = 0; k < 16; ++k) {
            float a[8], b[10];
            *reinterpret_cast<float4*>(&a[0]) = *reinterpret_cast<const float4*>(&Qt[k][mg*8]);
            *reinterpret_cast<float4*>(&a[4]) = *reinterpret_cast<const float4*>(&Qt[k][mg*8+4]);
            const float* bp = &Dt[w][k][ng*10];  // 8B aligned (ng*10 even)
#pragma unroll
            for (int j2 = 0; j2 < 5; ++j2)
                *reinterpret_cast<float2*>(&b[j2*2]) = *reinterpret_cast<const float2*>(&bp[j2*2]);
#pragma unroll
            for (int i = 0; i < 8; ++i)
#pragma unroll
                for (int j = 0; j < 10; ++j)
                    acc[i][j] = fmaf(a[i], b[j], acc[i][j]);
        }
        __syncthreads();
    }

    float dmv[10];
#pragma unroll
    for (int j = 0; j < 10; ++j)
        dmv[j] = dmask[(size_t)d * N_ + ng*10 + j];

    const float* gq = gum + ((size_t)q * ND_ + d) * ((size_t)M_ * N_);

    float partial = 0.0f;
#pragma unroll
    for (int i = 0; i < 8; ++i) {
        const int m = mg*8 + i;
        // x = sim_masked / TEMP  (masks are exact 0/1 -> select == dm*s+(1-dm)*NEG)
        float x[10];
        float mx = -3.402823466e38f;
#pragma unroll
        for (int j = 0; j < 10; ++j) {
            float sm = (dmv[j] != 0.0f) ? acc[i][j] : -10000.0f;
            x[j] = sm / 0.1f;                 // IEEE divide: bit-matches np
            mx = fmaxf(mx, x[j]);
        }
        mx = fmaxf(mx, __shfl_xor(mx, 1));
        mx = fmaxf(mx, __shfl_xor(mx, 2));
        mx = fmaxf(mx, __shfl_xor(mx, 4));
        mx = fmaxf(mx, __shfl_xor(mx, 8));

        float se = 0.0f;
#pragma unroll
        for (int j = 0; j < 10; ++j) se = __fadd_rn(se, expf(x[j] - mx));
        se = __fadd_rn(se, __shfl_xor(se, 1));
        se = __fadd_rn(se, __shfl_xor(se, 2));
        se = __fadd_rn(se, __shfl_xor(se, 4));
        se = __fadd_rn(se, __shfl_xor(se, 8));
        const float lse = logf(se);

        float g[10];
        const float2* gp = reinterpret_cast<const float2*>(&gq[(size_t)m * N_ + ng*10]);
#pragma unroll
        for (int j2 = 0; j2 < 5; ++j2)
            *reinterpret_cast<float2*>(&g[j2*2]) = gp[j2];

        float z[10];
        float mz = -3.402823466e38f;
#pragma unroll
        for (int j = 0; j < 10; ++j) {
            z[j] = ((x[j] - mx - lse) + g[j]) / 0.5f;
            mz = fmaxf(mz, z[j]);
        }
        mz = fmaxf(mz, __shfl_xor(mz, 1));
        mz = fmaxf(mz, __shfl_xor(mz, 2));
        mz = fmaxf(mz, __shfl_xor(mz, 4));
        mz = fmaxf(mz, __shfl_xor(mz, 8));

        float e2[10];
        float s2 = 0.0f;
#pragma unroll
        for (int j = 0; j < 10; ++j) { e2[j] = expf(z[j] - mz); s2 = __fadd_rn(s2, e2[j]); }
        s2 = __fadd_rn(s2, __shfl_xor(s2, 1));
        s2 = __fadd_rn(s2, __shfl_xor(s2, 2));
        s2 = __fadd_rn(s2, __shfl_xor(s2, 4));
        s2 = __fadd_rn(s2, __shfl_xor(s2, 8));

        // argmax of y_soft = e2/s2 with numpy first-index tie-break
        float besty = -1.0f; int bestn = 0x7fffffff; float bests = 0.0f;
#pragma unroll
        for (int j = 0; j < 10; ++j) {
            float y = e2[j] / s2;
            if (y > besty) {
                besty = y;
                bestn = ng*10 + j;
                bests = (dmv[j] != 0.0f) ? acc[i][j] : -10000.0f;
            }
        }
#pragma unroll
        for (int dl = 1; dl < 16; dl <<= 1) {
            float oy = __shfl_xor(besty, dl);
            int   on = __shfl_xor(bestn, dl);
            float os = __shfl_xor(bests, dl);
            if (oy > besty || (oy == besty && on < bestn)) {
                besty = oy; bestn = on; bests = os;
            }
        }
        const float qmv = qmask[q * M_ + m];
        if (ng == 0) partial = __fadd_rn(partial, __fmul_rn(bests, qmv));
    }
    // sum the 4 mg partials: ((m0..7 + m8..15) + (m16..23 + m24..31))
    // == numpy pairwise order for 32 elements.
    partial = __fadd_rn(partial, __shfl_xor(partial, 16));
    partial = __fadd_rn(partial, __shfl_xor(partial, 32));
    if (lane == 0) out[(size_t)q * ND_ + d] = partial;
}

// ---------------------------------------------------------------------------
extern "C" void kernel_launch(void* const* d_in, const int* in_sizes, int n_in,
                              void* d_out, int out_size, void* d_ws, size_t ws_size,
                              hipStream_t stream)
{
    const float* Q   = (const float*)d_in[0];   // (32,32,768)
    const float* D   = (const float*)d_in[1];   // (200,160,768)
    const float* qm  = (const float*)d_in[2];   // (32,32)
    const float* dm  = (const float*)d_in[3];   // (200,160)
    const float* gum = (const float*)d_in[4];   // (32,200,32,160)
    const float* W   = (const float*)d_in[5];   // (768,128)
    float* out = (float*)d_out;                 // (32,200)

    float* Qp = (float*)d_ws;                              // 1024*128 floats
    float* Dp = Qp + (size_t)NQ_ * M_ * DIM_;              // 32000*128 floats

    proj_norm_row_kernel<<<dim3(NQ_ * M_), dim3(128), 0, stream>>>(Q, W, Qp);
    proj_norm_tiled_kernel<<<dim3((ND_ * N_) / 128), dim3(256), 0, stream>>>(D, W, Dp);
    score_kernel<<<dim3(NQ_ * (ND_ / 4)), dim3(256), 0, stream>>>(Qp, Dp, qm, dm, gum, out);
}

// Round 2
// 503.865 us; speedup vs baseline: 1.1247x; 1.1247x over previous
//
#include <hip/hip_runtime.h>
#include <math.h>

#define NQ_   32
#define M_    32
#define ND_   200
#define N_    160
#define H_    768
#define DIM_  128
#define DROWS_ (ND_ * N_)          // 32000
#define QROWS_ (NQ_ * M_)          // 1024
#define TROWS_ (DROWS_ + QROWS_)   // 33024

// async global->LDS, 16B per lane: LDS dest = base + lane*16
__device__ __forceinline__ void gl_lds16(const float* g, float* l) {
    __builtin_amdgcn_global_load_lds(
        (const __attribute__((address_space(1))) unsigned int*)g,
        (__attribute__((address_space(3))) unsigned int*)l, 16, 0, 0);
}

// ---------------------------------------------------------------------------
// Merged projection: rows 0..31999 = D, 32000..33023 = Q. Tile 32 rows x 128
// cols, 128 threads (2 waves), per-thread 4x8. K-chunk 16. Output TRANSPOSED:
// DpT[d][k][n] (k-major), QpT[q][k][m] — so score staging is contiguous.
// ---------------------------------------------------------------------------
__global__ __launch_bounds__(128) void proj_kernel(
    const float* __restrict__ Dmat, const float* __restrict__ Qmat,
    const float* __restrict__ W, float* __restrict__ DpT,
    float* __restrict__ QpT)
{
    __shared__ float Xt[16][32];    // [k][row]
    __shared__ float Ws[16][128];   // [k][col]
    const int tid = threadIdx.x;
    const int rb  = blockIdx.x * 32;
    const int cg  = tid & 15;       // col group: cols cg*8..+7
    const int rg  = tid >> 4;       // row group 0..7: rows rg*4..+3

    float acc[4][8];
#pragma unroll
    for (int i = 0; i < 4; ++i)
#pragma unroll
        for (int j = 0; j < 8; ++j) acc[i][j] = 0.0f;

    for (int kc = 0; kc < H_; kc += 16) {
        {   // stage X chunk: 32 rows x 16 k = 128 float4, one per thread
            int row = tid >> 2, c4 = tid & 3;
            int r = rb + row;
            const float* xr = (r < DROWS_) ? (Dmat + (size_t)r * H_)
                                           : (Qmat + (size_t)(r - DROWS_) * H_);
            float4 v = *reinterpret_cast<const float4*>(xr + kc + c4 * 4);
            Xt[c4*4+0][row] = v.x;
            Xt[c4*4+1][row] = v.y;
            Xt[c4*4+2][row] = v.z;
            Xt[c4*4+3][row] = v.w;
        }
#pragma unroll
        for (int it = 0; it < 4; ++it) {   // stage W chunk: 512 float4
            int f = tid + it * 128;
            int wr = f >> 5, wc = f & 31;
            *reinterpret_cast<float4*>(&Ws[wr][wc*4]) =
                *reinterpret_cast<const float4*>(&W[(size_t)(kc + wr) * DIM_ + wc * 4]);
        }
        __syncthreads();
#pragma unroll
        for (int k = 0; k < 16; ++k) {
            float a[4], b[8];
            *reinterpret_cast<float4*>(&a[0]) = *reinterpret_cast<const float4*>(&Xt[k][rg*4]);
            *reinterpret_cast<float4*>(&b[0]) = *reinterpret_cast<const float4*>(&Ws[k][cg*8]);
            *reinterpret_cast<float4*>(&b[4]) = *reinterpret_cast<const float4*>(&Ws[k][cg*8+4]);
#pragma unroll
            for (int i = 0; i < 4; ++i)
#pragma unroll
                for (int j = 0; j < 8; ++j)
                    acc[i][j] = fmaf(a[i], b[j], acc[i][j]);
        }
        __syncthreads();
    }

    // L2-normalize rows; row r's 128 cols live in the 16 same-rg lanes
    // (consecutive lanes of one wave). Butterfly tree over cg.
#pragma unroll
    for (int i = 0; i < 4; ++i) {
        int r = rb + rg * 4 + i;
        float ss = 0.0f;
#pragma unroll
        for (int j = 0; j < 8; ++j) ss = __fadd_rn(ss, __fmul_rn(acc[i][j], acc[i][j]));
        ss = __fadd_rn(ss, __shfl_xor(ss, 1));
        ss = __fadd_rn(ss, __shfl_xor(ss, 2));
        ss = __fadd_rn(ss, __shfl_xor(ss, 4));
        ss = __fadd_rn(ss, __shfl_xor(ss, 8));
        float nrm = fmaxf(sqrtf(ss), 1e-12f);
        if (r < DROWS_) {
            int dd = r / 160, n = r - dd * 160;
            float* o = DpT + (size_t)dd * (DIM_ * N_) + n;
#pragma unroll
            for (int j = 0; j < 8; ++j)
                o[(size_t)(cg*8 + j) * N_] = acc[i][j] / nrm;
        } else {
            int rq = r - DROWS_;
            int qq = rq >> 5, m = rq & 31;
            float* o = QpT + (size_t)qq * (DIM_ * M_) + m;
#pragma unroll
            for (int j = 0; j < 8; ++j)
                o[(size_t)(cg*8 + j) * M_] = acc[i][j] / nrm;
        }
    }
}

// ---------------------------------------------------------------------------
// Score: one wave per (q,d). grid 6400 (q fast for DpT L2 reuse). K-chunk 8,
// LDS 6 KB/block -> high occupancy. Staging via global_load_lds (contiguous
// k-major chunks, no transpose, no ds_writes). Lane tile 8 rows x 10 cols.
// ---------------------------------------------------------------------------
__global__ __launch_bounds__(64) void score_kernel(
    const float* __restrict__ QpT, const float* __restrict__ DpT,
    const float* __restrict__ qmask, const float* __restrict__ dmask,
    const float* __restrict__ gum, float* __restrict__ out)
{
    __shared__ float Qt[8][32];     // [k][m]
    __shared__ float Dt[8][160];    // [k][n]
    const int lane = threadIdx.x;   // 0..63
    const int mg   = lane >> 4;     // rows mg*8..+7
    const int ng   = lane & 15;     // cols ng*10..+9
    const int q    = blockIdx.x & 31;
    const int d    = blockIdx.x >> 5;   // 0..199

    const float* Qb = QpT + (size_t)q * (DIM_ * M_);
    const float* Db = DpT + (size_t)d * (DIM_ * N_);

    float acc[8][10];
#pragma unroll
    for (int i = 0; i < 8; ++i)
#pragma unroll
        for (int j = 0; j < 10; ++j) acc[i][j] = 0.0f;

    for (int kc = 0; kc < DIM_; kc += 8) {
        // Qt chunk: 8x32 = 256 floats = 64 lanes x 16B, one call
        gl_lds16(Qb + kc * M_ + lane * 4, &Qt[0][0]);
        // Dt chunk: 8x160 = 1280 floats, 5 calls
#pragma unroll
        for (int c = 0; c < 5; ++c)
            gl_lds16(Db + kc * N_ + c * 256 + lane * 4, &Dt[0][0] + c * 256);
        __syncthreads();            // drains vmcnt -> LDS visible
#pragma unroll
        for (int k = 0; k < 8; ++k) {
            float a[8], b[10];
            *reinterpret_cast<float4*>(&a[0]) = *reinterpret_cast<const float4*>(&Qt[k][mg*8]);
            *reinterpret_cast<float4*>(&a[4]) = *reinterpret_cast<const float4*>(&Qt[k][mg*8+4]);
            const float* bp = &Dt[k][ng*10];    // 8B aligned, conflict-free banks
#pragma unroll
            for (int j2 = 0; j2 < 5; ++j2)
                *reinterpret_cast<float2*>(&b[j2*2]) = *reinterpret_cast<const float2*>(&bp[j2*2]);
#pragma unroll
            for (int i = 0; i < 8; ++i)
#pragma unroll
                for (int j = 0; j < 10; ++j)
                    acc[i][j] = fmaf(a[i], b[j], acc[i][j]);
        }
        __syncthreads();
    }

    float dmv[10];
#pragma unroll
    for (int j = 0; j < 10; ++j)
        dmv[j] = dmask[(size_t)d * N_ + ng*10 + j];

    const float* gq = gum + ((size_t)q * ND_ + d) * ((size_t)M_ * N_);

    float partial = 0.0f;
#pragma unroll
    for (int i = 0; i < 8; ++i) {
        const int m = mg*8 + i;
        float x[10];
        float mx = -3.402823466e38f;
#pragma unroll
        for (int j = 0; j < 10; ++j) {
            float sm = (dmv[j] != 0.0f) ? acc[i][j] : -10000.0f;
            x[j] = sm / 0.1f;                 // IEEE divide: bit-matches np
            mx = fmaxf(mx, x[j]);
        }
        mx = fmaxf(mx, __shfl_xor(mx, 1));
        mx = fmaxf(mx, __shfl_xor(mx, 2));
        mx = fmaxf(mx, __shfl_xor(mx, 4));
        mx = fmaxf(mx, __shfl_xor(mx, 8));

        float se = 0.0f;
#pragma unroll
        for (int j = 0; j < 10; ++j) se = __fadd_rn(se, expf(x[j] - mx));
        se = __fadd_rn(se, __shfl_xor(se, 1));
        se = __fadd_rn(se, __shfl_xor(se, 2));
        se = __fadd_rn(se, __shfl_xor(se, 4));
        se = __fadd_rn(se, __shfl_xor(se, 8));
        const float lse = logf(se);

        float g[10];
        const float2* gp = reinterpret_cast<const float2*>(&gq[(size_t)m * N_ + ng*10]);
#pragma unroll
        for (int j2 = 0; j2 < 5; ++j2)
            *reinterpret_cast<float2*>(&g[j2*2]) = gp[j2];

        float z[10];
        float mz = -3.402823466e38f;
#pragma unroll
        for (int j = 0; j < 10; ++j) {
            z[j] = ((x[j] - mx - lse) + g[j]) / 0.5f;
            mz = fmaxf(mz, z[j]);
        }
        mz = fmaxf(mz, __shfl_xor(mz, 1));
        mz = fmaxf(mz, __shfl_xor(mz, 2));
        mz = fmaxf(mz, __shfl_xor(mz, 4));
        mz = fmaxf(mz, __shfl_xor(mz, 8));

        float e2[10];
        float s2 = 0.0f;
#pragma unroll
        for (int j = 0; j < 10; ++j) { e2[j] = expf(z[j] - mz); s2 = __fadd_rn(s2, e2[j]); }
        s2 = __fadd_rn(s2, __shfl_xor(s2, 1));
        s2 = __fadd_rn(s2, __shfl_xor(s2, 2));
        s2 = __fadd_rn(s2, __shfl_xor(s2, 4));
        s2 = __fadd_rn(s2, __shfl_xor(s2, 8));

        // argmax of y_soft = e2/s2 with numpy first-index tie-break
        float besty = -1.0f; int bestn = 0x7fffffff; float bests = 0.0f;
#pragma unroll
        for (int j = 0; j < 10; ++j) {
            float y = e2[j] / s2;
            if (y > besty) {
                besty = y;
                bestn = ng*10 + j;
                bests = (dmv[j] != 0.0f) ? acc[i][j] : -10000.0f;
            }
        }
#pragma unroll
        for (int dl = 1; dl < 16; dl <<= 1) {
            float oy = __shfl_xor(besty, dl);
            int   on = __shfl_xor(bestn, dl);
            float os = __shfl_xor(bests, dl);
            if (oy > besty || (oy == besty && on < bestn)) {
                besty = oy; bestn = on; bests = os;
            }
        }
        const float qmv = qmask[q * M_ + m];
        if (ng == 0) partial = __fadd_rn(partial, __fmul_rn(bests, qmv));
    }
    // ((m0..7 + m8..15) + (m16..23 + m24..31)) == numpy pairwise order
    partial = __fadd_rn(partial, __shfl_xor(partial, 16));
    partial = __fadd_rn(partial, __shfl_xor(partial, 32));
    if (lane == 0) out[(size_t)q * ND_ + d] = partial;
}

// ---------------------------------------------------------------------------
extern "C" void kernel_launch(void* const* d_in, const int* in_sizes, int n_in,
                              void* d_out, int out_size, void* d_ws, size_t ws_size,
                              hipStream_t stream)
{
    const float* Q   = (const float*)d_in[0];   // (32,32,768)
    const float* D   = (const float*)d_in[1];   // (200,160,768)
    const float* qm  = (const float*)d_in[2];   // (32,32)
    const float* dm  = (const float*)d_in[3];   // (200,160)
    const float* gum = (const float*)d_in[4];   // (32,200,32,160)
    const float* W   = (const float*)d_in[5];   // (768,128)
    float* out = (float*)d_out;                 // (32,200)

    float* QpT = (float*)d_ws;                          // 32*128*32   = 131072 floats
    float* DpT = QpT + (size_t)QROWS_ * DIM_;           // 200*128*160 = 4.096M floats

    proj_kernel<<<dim3(TROWS_ / 32), dim3(128), 0, stream>>>(D, Q, W, DpT, QpT);
    score_kernel<<<dim3(NQ_ * ND_), dim3(64), 0, stream>>>(QpT, DpT, qm, dm, gum, out);
}